// Round 13
// baseline (479.000 us; speedup 1.0000x reference)
//
#include <hip/hip_runtime.h>
#include <hip/hip_bf16.h>

#define N_NODES 50000
#define N_EDGES 1600000
#define F_IN    128
#define F_OUT   8
#define K_TAPS  4
#define MAX_POWER 25     // F_OUT*(K_TAPS-1)+1

#define NBLK    256      // chain blocks (1 per CU)
#define NTHR    512
#define RPB     196      // rows per block (256*196 = 50176 >= 50000)
#define CHUNK   4096     // edges per partition block
#define NPART   391      // ceil(N_EDGES / CHUNK)
#define ECAP_G  8192     // global per-bucket slot stride (mean 6272)
#define ECAP_L  7168     // LDS edge-cache capacity (mean 6272, +11 sigma)
#define NITER   14       // ECAP_L / NTHR
#define CSB     800      // col-sort buckets (col>>6 < 782), padded

#define NCNT    16       // arrival counter lines (16 blocks per line)
#define LSTRIDE 16       // ints per counter line (64 B)

__device__ inline int wave_incl_scan(int v, int lane) {
    #pragma unroll
    for (int off = 1; off < 64; off <<= 1) {
        int t = __shfl_up(v, off, 64);
        if (lane >= off) v += t;
    }
    return v;
}

// sc1 ops: to L3 (coherence point), bypassing non-coherent per-XCD L2.
__device__ inline void st_coh(float* p, float v) {
    __hip_atomic_store(p, v, __ATOMIC_RELAXED, __HIP_MEMORY_SCOPE_AGENT);
}
__device__ inline int ld_coh_i(const int* p) {
    return __hip_atomic_load((int*)p, __ATOMIC_RELAXED, __HIP_MEMORY_SCOPE_AGENT);
}

// ---------------------------------------------------------------------------
// u[n] = sum_f x[n, f]   (separate kernel: kernel-boundary coherence is free)
// ---------------------------------------------------------------------------
__global__ void rowsum_kernel(const float* __restrict__ x,
                              float* __restrict__ u, int n_nodes) {
    int wave_in_block = threadIdx.x >> 6;
    int lane = threadIdx.x & 63;
    int node = blockIdx.x * 4 + wave_in_block;
    if (node >= n_nodes) return;
    const float2* xp = (const float2*)(x + (size_t)node * F_IN);
    float2 v = xp[lane];
    float s = v.x + v.y;
    #pragma unroll
    for (int off = 32; off > 0; off >>= 1)
        s += __shfl_down(s, off, 64);
    if (lane == 0) u[node] = s;
}

// ---------------------------------------------------------------------------
// Partition edges into fixed-stride bucket slots (bucket = row / RPB).
// LDS staging -> semi-coalesced run writes. Payload: ((row%RPB)<<16)|col, val.
// ---------------------------------------------------------------------------
__global__ void partition_kernel(const int* __restrict__ rows,
                                 const int* __restrict__ cols,
                                 const float* __restrict__ vals,
                                 int* __restrict__ gcnt,
                                 int2* __restrict__ edges, int n_edges) {
    __shared__ int lhist[NBLK];
    __shared__ int lcur[NBLK];
    __shared__ int lbase[NBLK];
    __shared__ int2 stage[CHUNK];
    __shared__ unsigned char sbkt[CHUNK];
    __shared__ int wsum[4];
    int tid = threadIdx.x;
    int base = blockIdx.x * CHUNK;
    int cend = min(base + CHUNK, n_edges);

    lhist[tid] = 0;
    __syncthreads();
    for (int i = base + tid; i < cend; i += 256)
        atomicAdd(&lhist[rows[i] / RPB], 1);
    __syncthreads();

    int lane = tid & 63, wid = tid >> 6;
    int h = lhist[tid];
    int incl = wave_incl_scan(h, lane);
    if (lane == 63) wsum[wid] = incl;
    __syncthreads();
    int woff = 0;
    for (int w = 0; w < wid; ++w) woff += wsum[w];
    int excl = woff + incl - h;
    lcur[tid] = excl;
    if (h) {
        int g = atomicAdd(&gcnt[tid], h);
        lbase[tid] = tid * ECAP_G + g - excl;
    }
    __syncthreads();

    for (int i = base + tid; i < cend; i += 256) {
        int r = rows[i], c = cols[i];
        float v = vals[i];
        int b = r / RPB;
        int pos = atomicAdd(&lcur[b], 1);
        stage[pos] = make_int2(((r - b * RPB) << 16) | c, __float_as_int(v));
        sbkt[pos] = (unsigned char)b;
    }
    __syncthreads();

    int cn = cend - base;
    for (int i = tid; i < cn; i += 256) {
        int b = sbkt[i];
        int o = lbase[b] + i;
        if (o - b * ECAP_G < ECAP_G)
            edges[o] = stage[i];
    }
}

// ---------------------------------------------------------------------------
// Persistent chain: 25 SpMV hops + y-fold. 256 blocks x 512 threads.
// Barrier: 16 monotone arrival counters (16 blocks/line, ~16 serialized RMWs),
// single-stage detection: wave 0's lanes 0-15 poll the 16 lines + __all.
// Poll traffic: 256 blocks x 16 lines per round (16x less than R10's flat).
// ---------------------------------------------------------------------------
__global__ __launch_bounds__(NTHR, 1)
void chain_kernel(const int* __restrict__ gcnt,
                  const int2* __restrict__ edges,
                  const float* __restrict__ coeff,
                  const float* __restrict__ u,
                  float* __restrict__ s,          // 25 * N_NODES
                  float* __restrict__ y,
                  int* __restrict__ bar_cnt,      // NCNT padded lines
                  int n_nodes) {
    __shared__ int2  esort[ECAP_L];
    __shared__ int   chist[CSB];
    __shared__ int   ccur[CSB];
    __shared__ int   wsum8[8];
    __shared__ float acc[RPB];
    __shared__ float yacc[RPB * F_OUT];
    __shared__ float lcoeff[F_OUT * K_TAPS];

    int tid = threadIdx.x;
    int b = blockIdx.x;

    if (tid < RPB) acc[tid] = 0.f;
    for (int j = tid; j < RPB * F_OUT; j += NTHR) yacc[j] = 0.f;
    if (tid < F_OUT * K_TAPS) lcoeff[tid] = coeff[tid];

    int cnt = min(gcnt[b], ECAP_G);
    const int2* eb = edges + (size_t)b * ECAP_G;

    // --- prologue: counting-sort edges by col>>6 into LDS, then registers ---
    for (int i = tid; i < CSB; i += NTHR) chist[i] = 0;
    __syncthreads();
    if (cnt <= ECAP_L) {
        for (int i = tid; i < cnt; i += NTHR) {
            int2 e = eb[i];
            atomicAdd(&chist[(e.x & 0xFFFF) >> 6], 1);
        }
        __syncthreads();
        int lane = tid & 63, wid = tid >> 6;
        int b0 = 2 * tid;
        int h0 = (b0 < CSB) ? chist[b0] : 0;
        int h1 = (b0 + 1 < CSB) ? chist[b0 + 1] : 0;
        int ps = h0 + h1;
        int incl = wave_incl_scan(ps, lane);
        if (lane == 63) wsum8[wid] = incl;
        __syncthreads();
        int woff = 0;
        for (int w = 0; w < wid; ++w) woff += wsum8[w];
        int ex = woff + incl - ps;
        if (b0 < CSB) ccur[b0] = ex;
        if (b0 + 1 < CSB) ccur[b0 + 1] = ex + h0;
        __syncthreads();
        for (int i = tid; i < cnt; i += NTHR) {
            int2 e = eb[i];
            int pos = atomicAdd(&ccur[(e.x & 0xFFFF) >> 6], 1);
            esort[pos] = e;
        }
        __syncthreads();
    } else {
        int cl = min(cnt, ECAP_L);
        for (int i = tid; i < cl; i += NTHR) esort[i] = eb[i];  // unsorted fallback
        __syncthreads();
    }

    // hop-invariant edge registers: ~13-14 edges per thread
    int   ecol[NITER];
    int   erow[NITER];
    float eval[NITER];
    int cntl = min(cnt, ECAP_L);
    #pragma unroll
    for (int j = 0; j < NITER; ++j) {
        int idx = tid + j * NTHR;
        int2 e = (idx < cntl) ? esort[idx] : make_int2(0, 0);
        ecol[j] = e.x & 0xFFFF;
        erow[j] = e.x >> 16;
        eval[j] = __int_as_float(e.y);
    }

    int myline = (b & (NCNT - 1)) * LSTRIDE;

    for (int p = 0; p < MAX_POWER; ++p) {
        const float* __restrict__ src = (p == 0) ? u : s + (size_t)(p - 1) * n_nodes;
        float* dst = s + (size_t)p * n_nodes;

        // gather: NITER independent cached loads, then LDS atomics
        float v[NITER];
        #pragma unroll
        for (int j = 0; j < NITER; ++j) v[j] = src[ecol[j]];
        #pragma unroll
        for (int j = 0; j < NITER; ++j)
            atomicAdd(&acc[erow[j]], eval[j] * v[j]);
        for (int k = ECAP_L + tid; k < cnt; k += NTHR) {  // overflow (never, seed 0)
            int2 ev = eb[k];
            atomicAdd(&acc[ev.x >> 16], __int_as_float(ev.y) * src[ev.x & 0xFFFF]);
        }
        __syncthreads();

        float val = (tid < RPB) ? acc[tid] : 0.f;
        int row = b * RPB + tid;
        bool last = (p == MAX_POWER - 1);
        if (!last && tid < RPB && row < n_nodes) st_coh(&dst[row], val);

        if (!last) {
            __syncthreads();                      // drain: dst sc1 stores L3-acked
            if (tid == 0)
                __hip_atomic_fetch_add(&bar_cnt[myline], 1,
                                       __ATOMIC_RELAXED, __HIP_MEMORY_SCOPE_AGENT);
        }
        // fold + reset hidden behind the barrier wait
        if (tid < RPB) {
            acc[tid] = 0.f;
            #pragma unroll
            for (int o = 0; o < F_OUT; ++o) {
                int k = p - (K_TAPS - 1) * o;     // tap index for output o
                if (k >= 0 && k < K_TAPS)
                    yacc[tid * F_OUT + o] += lcoeff[o * K_TAPS + k] * val;
            }
        }
        if (!last) {
            // single-stage detection: lanes 0-15 poll the 16 counter lines
            if (tid < 64) {
                int target = (NBLK / NCNT) * (p + 1);     // 16 * gen
                int vci = (tid < NCNT)
                        ? ld_coh_i(&bar_cnt[tid * LSTRIDE]) : target;
                while (!__all(vci >= target)) {
                    __builtin_amdgcn_s_sleep(2);
                    vci = (tid < NCNT)
                        ? ld_coh_i(&bar_cnt[tid * LSTRIDE]) : target;
                }
            }
            __syncthreads();
        }
    }

    __syncthreads();
    for (int j = tid; j < RPB * F_OUT; j += NTHR) {
        int row = b * RPB + (j >> 3);
        if (row < n_nodes) y[(size_t)row * F_OUT + (j & 7)] = yacc[j];
    }
}

extern "C" void kernel_launch(void* const* d_in, const int* in_sizes, int n_in,
                              void* d_out, int out_size, void* d_ws, size_t ws_size,
                              hipStream_t stream) {
    const float* x        = (const float*)d_in[0];
    const int*   gso_rows = (const int*)d_in[1];
    const int*   gso_cols = (const int*)d_in[2];
    const float* gso_vals = (const float*)d_in[3];
    const float* coeff    = (const float*)d_in[4];
    float* y = (float*)d_out;

    // ws layout: u[N] | s[25N] | edges[NBLK*ECAP_G] int2 | gcnt[NBLK]
    //            | bar_cnt[NCNT*LSTRIDE]
    float* u       = (float*)d_ws;
    float* s       = u + N_NODES;
    int2*  edges   = (int2*)(s + (size_t)MAX_POWER * N_NODES);  // 8B-aligned
    int*   gcnt    = (int*)(edges + (size_t)NBLK * ECAP_G);
    int*   bar_cnt = gcnt + NBLK;

    // zero control area (gcnt + counters) in one memset
    size_t ctrl_ints = (size_t)NBLK + (size_t)NCNT * LSTRIDE;
    hipMemsetAsync(gcnt, 0, ctrl_ints * sizeof(int), stream);

    // bucket partition (fixed-stride slots)
    partition_kernel<<<NPART, 256, 0, stream>>>(
        gso_rows, gso_cols, gso_vals, gcnt, edges, N_EDGES);

    // u = rowsum(x)  (plain stores; kernel boundary makes it coherent)
    rowsum_kernel<<<(N_NODES + 3) / 4, 256, 0, stream>>>(x, u, N_NODES);

    // fused persistent chain
    int n_nodes = N_NODES;
    void* args[] = { (void*)&gcnt, (void*)&edges, (void*)&coeff,
                     (void*)&u, (void*)&s, (void*)&y, (void*)&bar_cnt,
                     (void*)&n_nodes };
    hipLaunchCooperativeKernel((void*)chain_kernel, dim3(NBLK), dim3(NTHR),
                               args, 0, stream);
}

// Round 14
// 476.702 us; speedup vs baseline: 1.0048x; 1.0048x over previous
//
#include <hip/hip_runtime.h>
#include <hip/hip_bf16.h>

#define N_NODES 50000
#define N_EDGES 1600000
#define F_IN    128
#define F_OUT   8
#define K_TAPS  4
#define MAX_POWER 25     // F_OUT*(K_TAPS-1)+1

#define NBLK    256      // chain blocks (1 per CU)
#define NTHR    512
#define RPB     196      // rows per block (256*196 = 50176 >= 50000)
#define CHUNK   4096     // edges per partition block
#define NPART   391      // ceil(N_EDGES / CHUNK)
#define ECAP_G  8192     // global per-bucket slot stride (mean 6272)
#define ECAP_L  7168     // LDS edge-cache capacity (mean 6272, +11 sigma)
#define NITER   14       // ECAP_L / NTHR
#define CSB     800      // col-sort buckets (col>>6 < 782), padded

#define FSTRIDE 16       // ints per flag line (64 B)

__device__ inline int wave_incl_scan(int v, int lane) {
    #pragma unroll
    for (int off = 1; off < 64; off <<= 1) {
        int t = __shfl_up(v, off, 64);
        if (lane >= off) v += t;
    }
    return v;
}

// sc1 ops: to L3 (coherence point), bypassing non-coherent per-XCD L2.
__device__ inline void st_coh(float* p, float v) {
    __hip_atomic_store(p, v, __ATOMIC_RELAXED, __HIP_MEMORY_SCOPE_AGENT);
}
__device__ inline void st_coh_i(int* p, int v) {
    __hip_atomic_store(p, v, __ATOMIC_RELAXED, __HIP_MEMORY_SCOPE_AGENT);
}
__device__ inline int ld_coh_i(const int* p) {
    return __hip_atomic_load((int*)p, __ATOMIC_RELAXED, __HIP_MEMORY_SCOPE_AGENT);
}

// ---------------------------------------------------------------------------
// u[n] = sum_f x[n, f]   (separate kernel: kernel-boundary coherence is free)
// ---------------------------------------------------------------------------
__global__ void rowsum_kernel(const float* __restrict__ x,
                              float* __restrict__ u, int n_nodes) {
    int wave_in_block = threadIdx.x >> 6;
    int lane = threadIdx.x & 63;
    int node = blockIdx.x * 4 + wave_in_block;
    if (node >= n_nodes) return;
    const float2* xp = (const float2*)(x + (size_t)node * F_IN);
    float2 v = xp[lane];
    float s = v.x + v.y;
    #pragma unroll
    for (int off = 32; off > 0; off >>= 1)
        s += __shfl_down(s, off, 64);
    if (lane == 0) u[node] = s;
}

// ---------------------------------------------------------------------------
// Partition edges into fixed-stride bucket slots (bucket = row / RPB).
// LDS staging -> semi-coalesced run writes. Payload: ((row%RPB)<<16)|col, val.
// ---------------------------------------------------------------------------
__global__ void partition_kernel(const int* __restrict__ rows,
                                 const int* __restrict__ cols,
                                 const float* __restrict__ vals,
                                 int* __restrict__ gcnt,
                                 int2* __restrict__ edges, int n_edges) {
    __shared__ int lhist[NBLK];
    __shared__ int lcur[NBLK];
    __shared__ int lbase[NBLK];
    __shared__ int2 stage[CHUNK];
    __shared__ unsigned char sbkt[CHUNK];
    __shared__ int wsum[4];
    int tid = threadIdx.x;
    int base = blockIdx.x * CHUNK;
    int cend = min(base + CHUNK, n_edges);

    lhist[tid] = 0;
    __syncthreads();
    for (int i = base + tid; i < cend; i += 256)
        atomicAdd(&lhist[rows[i] / RPB], 1);
    __syncthreads();

    int lane = tid & 63, wid = tid >> 6;
    int h = lhist[tid];
    int incl = wave_incl_scan(h, lane);
    if (lane == 63) wsum[wid] = incl;
    __syncthreads();
    int woff = 0;
    for (int w = 0; w < wid; ++w) woff += wsum[w];
    int excl = woff + incl - h;
    lcur[tid] = excl;
    if (h) {
        int g = atomicAdd(&gcnt[tid], h);
        lbase[tid] = tid * ECAP_G + g - excl;
    }
    __syncthreads();

    for (int i = base + tid; i < cend; i += 256) {
        int r = rows[i], c = cols[i];
        float v = vals[i];
        int b = r / RPB;
        int pos = atomicAdd(&lcur[b], 1);
        stage[pos] = make_int2(((r - b * RPB) << 16) | c, __float_as_int(v));
        sbkt[pos] = (unsigned char)b;
    }
    __syncthreads();

    int cn = cend - base;
    for (int i = tid; i < cn; i += 256) {
        int b = sbkt[i];
        int o = lbase[b] + i;
        if (o - b * ECAP_G < ECAP_G)
            edges[o] = stage[i];
    }
}

// ---------------------------------------------------------------------------
// Persistent chain: 25 SpMV hops + y-fold. 256 blocks x 512 threads.
// Edges in registers (hop-invariant). Barrier = R10's flat distributed-poll
// (best measured): per-block monotone flag lines; tids 0-255 each poll one.
// ---------------------------------------------------------------------------
__global__ __launch_bounds__(NTHR, 1)
void chain_kernel(const int* __restrict__ gcnt,
                  const int2* __restrict__ edges,
                  const float* __restrict__ coeff,
                  const float* __restrict__ u,
                  float* __restrict__ s,          // 25 * N_NODES
                  float* __restrict__ y,
                  int* __restrict__ flags,        // NBLK padded lines
                  int n_nodes) {
    __shared__ int2  esort[ECAP_L];
    __shared__ int   chist[CSB];
    __shared__ int   ccur[CSB];
    __shared__ int   wsum8[8];
    __shared__ float acc[RPB];
    __shared__ float yacc[RPB * F_OUT];
    __shared__ float lcoeff[F_OUT * K_TAPS];

    int tid = threadIdx.x;
    int b = blockIdx.x;

    if (tid < RPB) acc[tid] = 0.f;
    for (int j = tid; j < RPB * F_OUT; j += NTHR) yacc[j] = 0.f;
    if (tid < F_OUT * K_TAPS) lcoeff[tid] = coeff[tid];

    int cnt = min(gcnt[b], ECAP_G);
    const int2* eb = edges + (size_t)b * ECAP_G;

    // --- prologue: counting-sort edges by col>>6 into LDS, then registers ---
    for (int i = tid; i < CSB; i += NTHR) chist[i] = 0;
    __syncthreads();
    if (cnt <= ECAP_L) {
        for (int i = tid; i < cnt; i += NTHR) {
            int2 e = eb[i];
            atomicAdd(&chist[(e.x & 0xFFFF) >> 6], 1);
        }
        __syncthreads();
        int lane = tid & 63, wid = tid >> 6;
        int b0 = 2 * tid;
        int h0 = (b0 < CSB) ? chist[b0] : 0;
        int h1 = (b0 + 1 < CSB) ? chist[b0 + 1] : 0;
        int ps = h0 + h1;
        int incl = wave_incl_scan(ps, lane);
        if (lane == 63) wsum8[wid] = incl;
        __syncthreads();
        int woff = 0;
        for (int w = 0; w < wid; ++w) woff += wsum8[w];
        int ex = woff + incl - ps;
        if (b0 < CSB) ccur[b0] = ex;
        if (b0 + 1 < CSB) ccur[b0 + 1] = ex + h0;
        __syncthreads();
        for (int i = tid; i < cnt; i += NTHR) {
            int2 e = eb[i];
            int pos = atomicAdd(&ccur[(e.x & 0xFFFF) >> 6], 1);
            esort[pos] = e;
        }
        __syncthreads();
    } else {
        int cl = min(cnt, ECAP_L);
        for (int i = tid; i < cl; i += NTHR) esort[i] = eb[i];  // unsorted fallback
        __syncthreads();
    }

    // hop-invariant edge registers: ~13-14 edges per thread
    int   ecol[NITER];
    int   erow[NITER];
    float eval[NITER];
    int cntl = min(cnt, ECAP_L);
    #pragma unroll
    for (int j = 0; j < NITER; ++j) {
        int idx = tid + j * NTHR;
        int2 e = (idx < cntl) ? esort[idx] : make_int2(0, 0);
        ecol[j] = e.x & 0xFFFF;
        erow[j] = e.x >> 16;
        eval[j] = __int_as_float(e.y);
    }

    for (int p = 0; p < MAX_POWER; ++p) {
        const float* __restrict__ src = (p == 0) ? u : s + (size_t)(p - 1) * n_nodes;
        float* dst = s + (size_t)p * n_nodes;

        // gather: NITER independent cached loads, then LDS atomics
        float v[NITER];
        #pragma unroll
        for (int j = 0; j < NITER; ++j) v[j] = src[ecol[j]];
        #pragma unroll
        for (int j = 0; j < NITER; ++j)
            atomicAdd(&acc[erow[j]], eval[j] * v[j]);
        for (int k = ECAP_L + tid; k < cnt; k += NTHR) {  // overflow (never, seed 0)
            int2 ev = eb[k];
            atomicAdd(&acc[ev.x >> 16], __int_as_float(ev.y) * src[ev.x & 0xFFFF]);
        }
        __syncthreads();

        float val = (tid < RPB) ? acc[tid] : 0.f;
        int row = b * RPB + tid;
        bool last = (p == MAX_POWER - 1);
        if (!last && tid < RPB && row < n_nodes) st_coh(&dst[row], val);

        if (!last) {
            __syncthreads();                      // drain: dst sc1 stores L3-acked
            if (tid == 0) st_coh_i(&flags[b * FSTRIDE], p + 1);
        }
        // fold + reset hidden behind the barrier wait
        if (tid < RPB) {
            acc[tid] = 0.f;
            #pragma unroll
            for (int o = 0; o < F_OUT; ++o) {
                int k = p - (K_TAPS - 1) * o;     // tap index for output o
                if (k >= 0 && k < K_TAPS)
                    yacc[tid * F_OUT + o] += lcoeff[o * K_TAPS + k] * val;
            }
        }
        if (!last) {
            if (tid < NBLK)
                while (ld_coh_i(&flags[tid * FSTRIDE]) < p + 1)
                    __builtin_amdgcn_s_sleep(2);
            __syncthreads();
        }
    }

    __syncthreads();
    for (int j = tid; j < RPB * F_OUT; j += NTHR) {
        int row = b * RPB + (j >> 3);
        if (row < n_nodes) y[(size_t)row * F_OUT + (j & 7)] = yacc[j];
    }
}

extern "C" void kernel_launch(void* const* d_in, const int* in_sizes, int n_in,
                              void* d_out, int out_size, void* d_ws, size_t ws_size,
                              hipStream_t stream) {
    const float* x        = (const float*)d_in[0];
    const int*   gso_rows = (const int*)d_in[1];
    const int*   gso_cols = (const int*)d_in[2];
    const float* gso_vals = (const float*)d_in[3];
    const float* coeff    = (const float*)d_in[4];
    float* y = (float*)d_out;

    // ws layout: u[N] | s[25N] | edges[NBLK*ECAP_G] int2 | gcnt[NBLK]
    //            | flags[NBLK*FSTRIDE]
    float* u     = (float*)d_ws;
    float* s     = u + N_NODES;
    int2*  edges = (int2*)(s + (size_t)MAX_POWER * N_NODES);  // 8B-aligned
    int*   gcnt  = (int*)(edges + (size_t)NBLK * ECAP_G);
    int*   flags = gcnt + NBLK;

    // zero control area (gcnt + flags) in one memset
    size_t ctrl_ints = (size_t)NBLK + (size_t)NBLK * FSTRIDE;
    hipMemsetAsync(gcnt, 0, ctrl_ints * sizeof(int), stream);

    // bucket partition (fixed-stride slots)
    partition_kernel<<<NPART, 256, 0, stream>>>(
        gso_rows, gso_cols, gso_vals, gcnt, edges, N_EDGES);

    // u = rowsum(x)  (plain stores; kernel boundary makes it coherent)
    rowsum_kernel<<<(N_NODES + 3) / 4, 256, 0, stream>>>(x, u, N_NODES);

    // fused persistent chain
    int n_nodes = N_NODES;
    void* args[] = { (void*)&gcnt, (void*)&edges, (void*)&coeff,
                     (void*)&u, (void*)&s, (void*)&y, (void*)&flags,
                     (void*)&n_nodes };
    hipLaunchCooperativeKernel((void*)chain_kernel, dim3(NBLK), dim3(NTHR),
                               args, 0, stream);
}

// Round 15
// 409.969 us; speedup vs baseline: 1.1684x; 1.1628x over previous
//
#include <hip/hip_runtime.h>
#include <hip/hip_bf16.h>

#define N_NODES 50000
#define N_EDGES 1600000
#define F_IN    128
#define F_OUT   8
#define K_TAPS  4
#define MAX_POWER 25     // F_OUT*(K_TAPS-1)+1

#define NBLK    256      // chain blocks (1 per CU)
#define NTHR    512
#define RPB     196      // rows per block (256*196 = 50176 >= 50000)
#define CHUNK   4096     // edges per partition block
#define NPART   391      // ceil(N_EDGES / CHUNK)
#define ECAP_G  8192     // global per-bucket slot stride (mean 6272)
#define ECAP_L  7168     // LDS edge-cache capacity (mean 6272, +11 sigma)
#define NITER   14       // ECAP_L / NTHR
#define CSB     800      // col-sort buckets (col>>6 < 782), padded

#define FSTRIDE 16       // ints per flag line (64 B)

__device__ inline int wave_incl_scan(int v, int lane) {
    #pragma unroll
    for (int off = 1; off < 64; off <<= 1) {
        int t = __shfl_up(v, off, 64);
        if (lane >= off) v += t;
    }
    return v;
}

// sc1 ops: to L3 (coherence point), bypassing non-coherent per-XCD L2.
__device__ inline void st_coh(float* p, float v) {
    __hip_atomic_store(p, v, __ATOMIC_RELAXED, __HIP_MEMORY_SCOPE_AGENT);
}
__device__ inline void st_coh_i(int* p, int v) {
    __hip_atomic_store(p, v, __ATOMIC_RELAXED, __HIP_MEMORY_SCOPE_AGENT);
}
__device__ inline int ld_coh_i(const int* p) {
    return __hip_atomic_load((int*)p, __ATOMIC_RELAXED, __HIP_MEMORY_SCOPE_AGENT);
}

// ---------------------------------------------------------------------------
// u[n] = sum_f x[n, f]   (separate kernel: kernel-boundary coherence is free)
// ---------------------------------------------------------------------------
__global__ void rowsum_kernel(const float* __restrict__ x,
                              float* __restrict__ u, int n_nodes) {
    int wave_in_block = threadIdx.x >> 6;
    int lane = threadIdx.x & 63;
    int node = blockIdx.x * 4 + wave_in_block;
    if (node >= n_nodes) return;
    const float2* xp = (const float2*)(x + (size_t)node * F_IN);
    float2 v = xp[lane];
    float s = v.x + v.y;
    #pragma unroll
    for (int off = 32; off > 0; off >>= 1)
        s += __shfl_down(s, off, 64);
    if (lane == 0) u[node] = s;
}

// ---------------------------------------------------------------------------
// Partition edges into fixed-stride bucket slots (bucket = row / RPB).
// LDS staging -> semi-coalesced run writes. Payload: ((row%RPB)<<16)|col, val.
// ---------------------------------------------------------------------------
__global__ void partition_kernel(const int* __restrict__ rows,
                                 const int* __restrict__ cols,
                                 const float* __restrict__ vals,
                                 int* __restrict__ gcnt,
                                 int2* __restrict__ edges, int n_edges) {
    __shared__ int lhist[NBLK];
    __shared__ int lcur[NBLK];
    __shared__ int lbase[NBLK];
    __shared__ int2 stage[CHUNK];
    __shared__ unsigned char sbkt[CHUNK];
    __shared__ int wsum[4];
    int tid = threadIdx.x;
    int base = blockIdx.x * CHUNK;
    int cend = min(base + CHUNK, n_edges);

    lhist[tid] = 0;
    __syncthreads();
    for (int i = base + tid; i < cend; i += 256)
        atomicAdd(&lhist[rows[i] / RPB], 1);
    __syncthreads();

    int lane = tid & 63, wid = tid >> 6;
    int h = lhist[tid];
    int incl = wave_incl_scan(h, lane);
    if (lane == 63) wsum[wid] = incl;
    __syncthreads();
    int woff = 0;
    for (int w = 0; w < wid; ++w) woff += wsum[w];
    int excl = woff + incl - h;
    lcur[tid] = excl;
    if (h) {
        int g = atomicAdd(&gcnt[tid], h);
        lbase[tid] = tid * ECAP_G + g - excl;
    }
    __syncthreads();

    for (int i = base + tid; i < cend; i += 256) {
        int r = rows[i], c = cols[i];
        float v = vals[i];
        int b = r / RPB;
        int pos = atomicAdd(&lcur[b], 1);
        stage[pos] = make_int2(((r - b * RPB) << 16) | c, __float_as_int(v));
        sbkt[pos] = (unsigned char)b;
    }
    __syncthreads();

    int cn = cend - base;
    for (int i = tid; i < cn; i += 256) {
        int b = sbkt[i];
        int o = lbase[b] + i;
        if (o - b * ECAP_G < ECAP_G)
            edges[o] = stage[i];
    }
}

// ---------------------------------------------------------------------------
// Persistent chain: 25 SpMV hops + y-fold. 256 blocks x 512 threads.
// Register edges; GUARDED tail (no padded same-address LDS atomics — that
// serialization was the R11-R14 regression). Flat distributed-poll barrier.
// ---------------------------------------------------------------------------
__global__ __launch_bounds__(NTHR, 1)
void chain_kernel(const int* __restrict__ gcnt,
                  const int2* __restrict__ edges,
                  const float* __restrict__ coeff,
                  const float* __restrict__ u,
                  float* __restrict__ s,          // 25 * N_NODES
                  float* __restrict__ y,
                  int* __restrict__ flags,        // NBLK padded lines
                  int n_nodes) {
    __shared__ int2  esort[ECAP_L];
    __shared__ int   chist[CSB];
    __shared__ int   ccur[CSB];
    __shared__ int   wsum8[8];
    __shared__ float acc[RPB];
    __shared__ float yacc[RPB * F_OUT];
    __shared__ float lcoeff[F_OUT * K_TAPS];

    int tid = threadIdx.x;
    int b = blockIdx.x;

    if (tid < RPB) acc[tid] = 0.f;
    for (int j = tid; j < RPB * F_OUT; j += NTHR) yacc[j] = 0.f;
    if (tid < F_OUT * K_TAPS) lcoeff[tid] = coeff[tid];

    int cnt = min(gcnt[b], ECAP_G);
    const int2* eb = edges + (size_t)b * ECAP_G;

    // --- prologue: counting-sort edges by col>>6 into LDS, then registers ---
    for (int i = tid; i < CSB; i += NTHR) chist[i] = 0;
    __syncthreads();
    if (cnt <= ECAP_L) {
        for (int i = tid; i < cnt; i += NTHR) {
            int2 e = eb[i];
            atomicAdd(&chist[(e.x & 0xFFFF) >> 6], 1);
        }
        __syncthreads();
        int lane = tid & 63, wid = tid >> 6;
        int b0 = 2 * tid;
        int h0 = (b0 < CSB) ? chist[b0] : 0;
        int h1 = (b0 + 1 < CSB) ? chist[b0 + 1] : 0;
        int ps = h0 + h1;
        int incl = wave_incl_scan(ps, lane);
        if (lane == 63) wsum8[wid] = incl;
        __syncthreads();
        int woff = 0;
        for (int w = 0; w < wid; ++w) woff += wsum8[w];
        int ex = woff + incl - ps;
        if (b0 < CSB) ccur[b0] = ex;
        if (b0 + 1 < CSB) ccur[b0 + 1] = ex + h0;
        __syncthreads();
        for (int i = tid; i < cnt; i += NTHR) {
            int2 e = eb[i];
            int pos = atomicAdd(&ccur[(e.x & 0xFFFF) >> 6], 1);
            esort[pos] = e;
        }
        __syncthreads();
    } else {
        int cl = min(cnt, ECAP_L);
        for (int i = tid; i < cl; i += NTHR) esort[i] = eb[i];  // unsorted fallback
        __syncthreads();
    }

    // hop-invariant edge registers: ~12-14 edges per thread
    int   ecol[NITER];
    int   erow[NITER];
    float eval[NITER];
    int cntl = min(cnt, ECAP_L);
    #pragma unroll
    for (int j = 0; j < NITER; ++j) {
        int idx = tid + j * NTHR;
        int2 e = (idx < cntl) ? esort[idx] : make_int2(0, 0);
        ecol[j] = e.x & 0xFFFF;
        erow[j] = e.x >> 16;
        eval[j] = __int_as_float(e.y);
    }

    for (int p = 0; p < MAX_POWER; ++p) {
        const float* __restrict__ src = (p == 0) ? u : s + (size_t)(p - 1) * n_nodes;
        float* dst = s + (size_t)p * n_nodes;

        // gather: unconditional loads (full MLP; padded ecol=0 is L2-hot),
        // GUARDED atomics (no serialized same-address padding adds)
        float v[NITER];
        #pragma unroll
        for (int j = 0; j < NITER; ++j) v[j] = src[ecol[j]];
        #pragma unroll
        for (int j = 0; j < NITER; ++j)
            if (tid + j * NTHR < cntl)
                atomicAdd(&acc[erow[j]], eval[j] * v[j]);
        for (int k = ECAP_L + tid; k < cnt; k += NTHR) {  // overflow (never, seed 0)
            int2 ev = eb[k];
            atomicAdd(&acc[ev.x >> 16], __int_as_float(ev.y) * src[ev.x & 0xFFFF]);
        }
        __syncthreads();

        float val = (tid < RPB) ? acc[tid] : 0.f;
        int row = b * RPB + tid;
        bool last = (p == MAX_POWER - 1);
        if (!last && tid < RPB && row < n_nodes) st_coh(&dst[row], val);

        if (!last) {
            __syncthreads();                      // drain: dst sc1 stores L3-acked
            if (tid == 0) st_coh_i(&flags[b * FSTRIDE], p + 1);
        }
        // fold + reset hidden behind the barrier wait
        if (tid < RPB) {
            acc[tid] = 0.f;
            #pragma unroll
            for (int o = 0; o < F_OUT; ++o) {
                int k = p - (K_TAPS - 1) * o;     // tap index for output o
                if (k >= 0 && k < K_TAPS)
                    yacc[tid * F_OUT + o] += lcoeff[o * K_TAPS + k] * val;
            }
        }
        if (!last) {
            if (tid < NBLK)
                while (ld_coh_i(&flags[tid * FSTRIDE]) < p + 1)
                    __builtin_amdgcn_s_sleep(2);
            __syncthreads();
        }
    }

    __syncthreads();
    for (int j = tid; j < RPB * F_OUT; j += NTHR) {
        int row = b * RPB + (j >> 3);
        if (row < n_nodes) y[(size_t)row * F_OUT + (j & 7)] = yacc[j];
    }
}

extern "C" void kernel_launch(void* const* d_in, const int* in_sizes, int n_in,
                              void* d_out, int out_size, void* d_ws, size_t ws_size,
                              hipStream_t stream) {
    const float* x        = (const float*)d_in[0];
    const int*   gso_rows = (const int*)d_in[1];
    const int*   gso_cols = (const int*)d_in[2];
    const float* gso_vals = (const float*)d_in[3];
    const float* coeff    = (const float*)d_in[4];
    float* y = (float*)d_out;

    // ws layout: u[N] | s[25N] | edges[NBLK*ECAP_G] int2 | gcnt[NBLK]
    //            | flags[NBLK*FSTRIDE]
    float* u     = (float*)d_ws;
    float* s     = u + N_NODES;
    int2*  edges = (int2*)(s + (size_t)MAX_POWER * N_NODES);  // 8B-aligned
    int*   gcnt  = (int*)(edges + (size_t)NBLK * ECAP_G);
    int*   flags = gcnt + NBLK;

    // zero control area (gcnt + flags) in one memset
    size_t ctrl_ints = (size_t)NBLK + (size_t)NBLK * FSTRIDE;
    hipMemsetAsync(gcnt, 0, ctrl_ints * sizeof(int), stream);

    // bucket partition (fixed-stride slots)
    partition_kernel<<<NPART, 256, 0, stream>>>(
        gso_rows, gso_cols, gso_vals, gcnt, edges, N_EDGES);

    // u = rowsum(x)  (plain stores; kernel boundary makes it coherent)
    rowsum_kernel<<<(N_NODES + 3) / 4, 256, 0, stream>>>(x, u, N_NODES);

    // fused persistent chain
    int n_nodes = N_NODES;
    void* args[] = { (void*)&gcnt, (void*)&edges, (void*)&coeff,
                     (void*)&u, (void*)&s, (void*)&y, (void*)&flags,
                     (void*)&n_nodes };
    hipLaunchCooperativeKernel((void*)chain_kernel, dim3(NBLK), dim3(NTHR),
                               args, 0, stream);
}